// Round 1
// 377.065 us; speedup vs baseline: 1.0549x; 1.0549x over previous
//
#include <hip/hip_runtime.h>
#include <hip/hip_bf16.h>

typedef unsigned short u16t;
typedef unsigned int   u32t;
typedef float  f32x4 __attribute__((ext_vector_type(4)));
typedef short  s16x8 __attribute__((ext_vector_type(8)));
typedef unsigned int u32x4 __attribute__((ext_vector_type(4)));
typedef float  f4 __attribute__((ext_vector_type(4)));

#define BB 2
#define TT 2048
#define CC 2048
#define HH 16
#define KVHN 4
#define DD 128
#define EPSV 1.1920929e-07f
#define SCALE 0.08838834764831845f
#define MFIX 12.0f   // fixed softmax max: |q.k|*SCALE <= sqrt(128)*(1+bf16 err) < 11.5

__device__ __forceinline__ float b2f(u16t u){ union{u32t i; float f;} x; x.i=((u32t)u)<<16; return x.f; }
__device__ __forceinline__ u16t f2b(float f){ union{float f; u32t i;} x; x.f=f; u32t r = x.i + 0x7fffu + ((x.i>>16)&1u); return (u16t)(r>>16); }
__device__ __forceinline__ u32t pk2(float a, float b){
    __hip_bfloat162 h = __float22bfloat162_rn(make_float2(a,b));
    u32t r; __builtin_memcpy(&r,&h,4); return r;
}
__device__ __forceinline__ s16x8 ldf(const u16t* p){ s16x8 r; __builtin_memcpy(&r,p,16); return r; }
__device__ __forceinline__ void st16(u16t* p, u32x4 v){ __builtin_memcpy(p,&v,16); }
__device__ __forceinline__ u32x4 ldg16(const u16t* p){ u32x4 r; __builtin_memcpy(&r,p,16); return r; }

// async global->LDS, 16B per lane; LDS dest = wave-uniform base + lane*16
typedef const __attribute__((address_space(1))) unsigned int ga_u32;
typedef __attribute__((address_space(3))) unsigned int ls_u32;
__device__ __forceinline__ void gl16(const u16t* g, u16t* l) {
    __builtin_amdgcn_global_load_lds((ga_u32*)(unsigned long long)(g),
                                     (ls_u32*)(unsigned int)(unsigned long long)(l),
                                     16, 0, 0);
}

#define BARRIER() __builtin_amdgcn_s_barrier()
#define SCHEDB()  __builtin_amdgcn_sched_barrier(0)
#define WAITLG0() asm volatile("s_waitcnt lgkmcnt(0)" ::: "memory")
#define WAITVM8() asm volatile("s_waitcnt vmcnt(8)" ::: "memory")
#define WAITVM0() asm volatile("s_waitcnt vmcnt(0)" ::: "memory")

// ---------------- Kernel 0: fp32 -> bf16 conversion ----------------
__global__ __launch_bounds__(256) void cvt_kernel(
    const float* __restrict__ x,  const float* __restrict__ wq,
    const float* __restrict__ wk, const float* __restrict__ wv,
    const float* __restrict__ wo,
    u16t* __restrict__ xb, u16t* __restrict__ wqb, u16t* __restrict__ wkb,
    u16t* __restrict__ wvb, u16t* __restrict__ wob)
{
    size_t g = (size_t)blockIdx.x * 256 + threadIdx.x;
    const float* src; u16t* dst; size_t off;
    if      (g < 1048576) { src = x;  dst = xb;  off = g; }
    else if (g < 1572864) { src = wq; dst = wqb; off = g - 1048576; }
    else if (g < 1703936) { src = wk; dst = wkb; off = g - 1572864; }
    else if (g < 1835008) { src = wv; dst = wvb; off = g - 1703936; }
    else                  { src = wo; dst = wob; off = g - 1835008; }
    f4 a = *(const f4*)(src + off*8);
    f4 b = *(const f4*)(src + off*8 + 4);
    u32x4 o = { pk2(a[0],a[1]), pk2(a[2],a[3]), pk2(b[0],b[1]), pk2(b[2],b[3]) };
    st16(dst + off*8, o);
}

// ---------------- Shared 256x256 8-phase GEMM core ----------------
// C = A @ B^T  (A [M][CC], B rows = output cols, both bf16, K = CC = 2048)
// 512 threads = 8 waves, wave grid 4M x 2N, wave tile 64 x 128, acc[4][8].
// LDS: 2 x (A[256][64] + B[256][64]) bf16 = 128 KiB, double-buffered K-tiles.
// Swizzle: 16B granule g at row r lives at LDS granule g ^ (r&7)
//  -> staged via inverse-swizzled GLOBAL source (gl16 dest must be linear),
//  -> read back with swizzled ds_read address. 16-way conflict -> 2-way (free).
// vmcnt discipline: kt0+kt1 staged in prologue (16 loads/thread outstanding);
// each iter waits vmcnt(8) (own tile landed, next in flight), computes 4 phases
// {ds_read | barrier | lgkmcnt(0) | setprio(1) 16xMFMA setprio(0) | barrier},
// then restages its own (just-read) buffer with kt+2. Never drains in-loop.
__device__ __forceinline__ void gemm256(
    const u16t* __restrict__ aPanel, const u16t* __restrict__ bPanel,
    u16t* lds, f32x4 (&acc)[4][8], const int tid)
{
    u16t* Abuf[2] = { lds,         lds + 32768 };
    u16t* Bbuf[2] = { lds + 16384, lds + 49152 };
    const int w = tid>>6, quad = (tid>>4)&3, l15 = tid&15;
    const int wr = (w>>1)*64, wc = (w&1)*128;
    // staging: granule id g = i*512 + tid, row = g>>3, src col granule = (g&7)^(row&7)
    // (i*64 is 0 mod 8, so the swizzled col granule is i-independent)
    const int gcol = (((tid&7) ^ ((tid>>3)&7)) << 3);
    const u16t* aB = aPanel + (size_t)(tid>>3)*CC + gcol;
    const u16t* bB = bPanel + (size_t)(tid>>3)*CC + gcol;

    #pragma unroll
    for (int i=0;i<4;++i)
        #pragma unroll
        for (int j=0;j<8;++j)
            #pragma unroll
            for (int r=0;r<4;++r) acc[i][j][r] = 0.f;

    // prologue: stage kt0 -> buf0, kt1 -> buf1 (16 loads/thread in flight)
    #pragma unroll
    for (int i=0;i<4;++i){
        gl16(aB + (size_t)i*64*CC,      Abuf[0] + (i*512+tid)*8);
        gl16(bB + (size_t)i*64*CC,      Bbuf[0] + (i*512+tid)*8);
    }
    #pragma unroll
    for (int i=0;i<4;++i){
        gl16(aB + (size_t)i*64*CC + 64, Abuf[1] + (i*512+tid)*8);
        gl16(bB + (size_t)i*64*CC + 64, Bbuf[1] + (i*512+tid)*8);
    }

    s16x8 af[4], bf[4];
    #pragma unroll 2
    for (int kt=0; kt<32; ++kt){
        u16t* Ab = Abuf[kt&1];
        u16t* Bb = Bbuf[kt&1];
        if (kt == 31) { WAITVM0(); } else { WAITVM8(); }   // own tile landed
        SCHEDB();
        BARRIER();                                          // all waves' tiles visible
        #pragma unroll
        for (int ph=0; ph<4; ++ph){
            const int kh = ph>>1, nh = ph&1;
            if (nh == 0){
                #pragma unroll
                for (int mi=0;mi<4;++mi){
                    const int row = wr + mi*16 + l15;
                    af[mi] = ldf(Ab + row*64 + ((((kh<<2)|quad) ^ (row&7))<<3));
                }
            }
            #pragma unroll
            for (int ni=0;ni<4;++ni){
                const int row = wc + nh*64 + ni*16 + l15;
                bf[ni] = ldf(Bb + row*64 + ((((kh<<2)|quad) ^ (row&7))<<3));
            }
            BARRIER();
            WAITLG0();
            SCHEDB();   // rule 18: stop MFMA hoisting above the lgkmcnt
            __builtin_amdgcn_s_setprio(1);
            #pragma unroll
            for (int mi=0;mi<4;++mi)
                #pragma unroll
                for (int ni=0;ni<4;++ni)
                    acc[mi][(nh<<2)|ni] = __builtin_amdgcn_mfma_f32_16x16x32_bf16(
                        af[mi], bf[ni], acc[mi][(nh<<2)|ni], 0,0,0);
            __builtin_amdgcn_s_setprio(0);
            SCHEDB();
            BARRIER();  // after this, every wave has lgkm-drained its reads of this buf
        }
        if (kt < 30){   // restage the buffer we just finished reading with kt+2
            const int k0 = (kt+2)*64;
            #pragma unroll
            for (int i=0;i<4;++i){
                gl16(aB + (size_t)i*64*CC + k0, Ab + (i*512+tid)*8);
                gl16(bB + (size_t)i*64*CC + k0, Bb + (i*512+tid)*8);
            }
        }
    }
}

// ---------------- Kernel 1: QKV GEMM + in-register RoPE + RMSNorm ----------------
// grid (16, 12): by<8 -> Q (2 heads/block), by in {8,9} -> K, {10,11} -> V.
// Wave owns full 128-wide head: RoPE pair (d, d+64) = acc[mi][ni] / acc[mi][ni+4],
// same lane. RMS is rotation-invariant -> computed pre-RoPE via 4x shfl_xor.
__global__ __launch_bounds__(512,2) void qkv_kernel(
    const u16t* __restrict__ xb, const u16t* __restrict__ wqb,
    const u16t* __restrict__ wkb, const u16t* __restrict__ wvb,
    const float* __restrict__ cosp, const float* __restrict__ sinp,
    u16t* __restrict__ qws, u16t* __restrict__ kws, u16t* __restrict__ vtw)
{
    __shared__ u16t lds[65536];
    const int tid = threadIdx.x;
    const int bx = blockIdx.x, by = blockIdx.y;
    const int m0 = bx*256;

    int type, headbase; const u16t* W;
    if (by < 8)       { type=0; W = wqb + (size_t)by*256*CC;      headbase = by*2; }
    else if (by < 10) { type=1; W = wkb + (size_t)(by-8)*256*CC;  headbase = (by-8)*2; }
    else              { type=2; W = wvb + (size_t)(by-10)*256*CC; headbase = (by-10)*2; }

    f32x4 acc[4][8];
    gemm256(xb + (size_t)m0*CC, W, lds, acc, tid);

    const int w = tid>>6, quad = (tid>>4)&3, l15 = tid&15;
    const int wr = (w>>1)*64, wn = w&1;
    const int head = headbase + wn;
    const int bb = bx>>3;
    const int ttb = (m0 + wr) & 2047;

    if (type == 2){
        // V: store transposed vt[b][kvh][d][t]
        u16t* vb = vtw + (size_t)(bb*KVHN+head)*DD*TT;
        #pragma unroll
        for (int mi=0;mi<4;++mi){
            const int tt = ttb + mi*16 + quad*4;
            #pragma unroll
            for (int ni=0;ni<8;++ni){
                const int d = ni*16 + l15;
                u16t o[4];
                #pragma unroll
                for (int r=0;r<4;++r) o[r] = f2b(acc[mi][ni][r]);
                __builtin_memcpy(vb + (size_t)d*TT + tt, o, 8);
            }
        }
    } else {
        u16t* dst = (type==0) ? (qws + (size_t)(bb*HH+head)*TT*DD)
                              : (kws + (size_t)(bb*KVHN+head)*TT*DD);
        #pragma unroll
        for (int mi=0;mi<4;++mi){
            const int tt0 = ttb + mi*16 + quad*4;
            float ss[4] = {0.f,0.f,0.f,0.f};
            #pragma unroll
            for (int ni=0;ni<8;++ni)
                #pragma unroll
                for (int r=0;r<4;++r) ss[r] += acc[mi][ni][r]*acc[mi][ni][r];
            float rms[4];
            #pragma unroll
            for (int r=0;r<4;++r){
                float s = ss[r];
                s += __shfl_xor(s, 1, 16);
                s += __shfl_xor(s, 2, 16);
                s += __shfl_xor(s, 4, 16);
                s += __shfl_xor(s, 8, 16);
                rms[r] = rsqrtf(s*(1.f/128.f) + EPSV);
            }
            #pragma unroll
            for (int ni=0;ni<4;++ni){
                const int j = ni*16 + l15;
                #pragma unroll
                for (int r=0;r<4;++r){
                    const int tt = tt0 + r;
                    const float c = cosp[tt*64 + j];
                    const float s = sinp[tt*64 + j];
                    const float z1 = acc[mi][ni][r], z2 = acc[mi][ni+4][r];
                    dst[(size_t)tt*DD + j]      = f2b((z1*c + z2*s)*rms[r]);
                    dst[(size_t)tt*DD + j + 64] = f2b((z2*c - z1*s)*rms[r]);
                }
            }
        }
    }
}

// ---------------- Kernel 2: causal flash attention (unchanged) ----------------
__global__ __launch_bounds__(256) void attn_kernel(
    const u16t* __restrict__ qws, const u16t* __restrict__ kws,
    const u16t* __restrict__ vtw, u16t* __restrict__ yws)
{
    __shared__ u16t lds[27136];       // 54272 B
    u16t* Qs = lds;                   // [128][136] (dead after frag load)
    u16t* Ks = lds;                   // [64][136]
    u16t* Vt = lds + 8704;            // [128][72]  V^T tile [d][kv]
    u16t* Ps = lds + 17920;           // [128][72]  per-wave P slices

    const int tid = threadIdx.x;
    const int w = tid>>6, lane = tid&63, quad = lane>>4, l15 = lane&15;
    const int qti = 15 - blockIdx.x;  // long blocks dispatch first
    const int q0 = qti*128;
    const int h = blockIdx.y, b = blockIdx.z, kvh = h>>2;

    const u16t* qb = qws + ((size_t)(b*HH+h)*TT + q0)*DD;
    const u16t* kb = kws + (size_t)(b*KVHN+kvh)*TT*DD;
    const u16t* vb = vtw + (size_t)(b*KVHN+kvh)*DD*TT;

    {   // stage Q tile
        const int row = tid>>1, c = (tid&1)*64;
        #pragma unroll
        for (int u=0;u<8;++u)
            st16(&Qs[row*136 + c + u*8], ldg16(qb + (size_t)row*DD + c + u*8));
    }
    __syncthreads();
    s16x8 qf[2][4];
    #pragma unroll
    for (int mi=0;mi<2;++mi)
        #pragma unroll
        for (int kq=0;kq<4;++kq)
            qf[mi][kq] = ldf(&Qs[(w*32+mi*16+l15)*136 + kq*32 + quad*8]);

    f32x4 o_[2][8];
    float l_[2][4];
    #pragma unroll
    for (int mi=0;mi<2;++mi){
        #pragma unroll
        for (int r=0;r<4;++r) l_[mi][r] = 0.f;
        #pragma unroll
        for (int n8=0;n8<8;++n8)
            #pragma unroll
            for (int r=0;r<4;++r) o_[mi][n8][r] = 0.f;
    }

    const int nkt = (qti+1)*2;
    const int qwbase = q0 + w*32;

    for (int kt=0; kt<nkt; ++kt){
        const int k0 = kt*64;
        __syncthreads();
        {
            const int kv = tid>>2, c4 = (tid&3)*32;
            #pragma unroll
            for (int u=0;u<4;++u)
                st16(&Ks[kv*136 + c4 + u*8], ldg16(kb + (size_t)(k0+kv)*DD + c4 + u*8));
            const int d = tid>>1, c2 = (tid&1)*32;
            #pragma unroll
            for (int u=0;u<4;++u)
                st16(&Vt[d*72 + c2 + u*8], ldg16(vb + (size_t)d*TT + k0 + c2 + u*8));
        }
        __syncthreads();
        if (k0 > qwbase + 31) continue;   // wave-uniform: fully masked for this wave

        // S = Q K^T
        f32x4 s[2][4];
        #pragma unroll
        for (int mi=0;mi<2;++mi)
            #pragma unroll
            for (int ni=0;ni<4;++ni)
                #pragma unroll
                for (int r=0;r<4;++r) s[mi][ni][r] = 0.f;
        #pragma unroll
        for (int kq=0;kq<4;++kq){
            s16x8 kf[4];
            #pragma unroll
            for (int ni=0;ni<4;++ni) kf[ni] = ldf(&Ks[(ni*16+l15)*136 + kq*32 + quad*8]);
            #pragma unroll
            for (int mi=0;mi<2;++mi)
                #pragma unroll
                for (int ni=0;ni<4;++ni)
                    s[mi][ni] = __builtin_amdgcn_mfma_f32_16x16x32_bf16(qf[mi][kq], kf[ni], s[mi][ni], 0,0,0);
        }

        // fixed-max softmax: p = exp(s*SCALE - 12); l accumulates per-lane partials
        const bool need_mask = (k0 + 63) > qwbase;
        #pragma unroll
        for (int mi=0;mi<2;++mi){
            const int qrow = qwbase + mi*16 + quad*4;
            #pragma unroll
            for (int ni=0;ni<4;++ni){
                const int kcol = k0 + ni*16 + l15;
                #pragma unroll
                for (int r=0;r<4;++r){
                    float p = __expf(__builtin_fmaf(s[mi][ni][r], SCALE, -MFIX));
                    if (need_mask && kcol > qrow + r) p = 0.f;
                    l_[mi][r] += p;
                    Ps[(w*32+mi*16+quad*4+r)*72 + ni*16 + l15] = f2b(p);
                }
            }
        }

        // O += P V  (same-wave LDS round-trip; DS ops in-order, no barrier)
        #pragma unroll
        for (int ks=0;ks<2;++ks){
            s16x8 pf[2];
            #pragma unroll
            for (int mi=0;mi<2;++mi)
                pf[mi] = ldf(&Ps[(w*32+mi*16+l15)*72 + ks*32 + quad*8]);
            #pragma unroll
            for (int n8=0;n8<8;++n8){
                s16x8 vf = ldf(&Vt[(n8*16+l15)*72 + ks*32 + quad*8]);
                #pragma unroll
                for (int mi=0;mi<2;++mi)
                    o_[mi][n8] = __builtin_amdgcn_mfma_f32_16x16x32_bf16(pf[mi], vf, o_[mi][n8], 0,0,0);
            }
        }
    }

    // epilogue: reduce l across the 16 col-lanes, normalize, store y[b][t][h*128+d]
    #pragma unroll
    for (int mi=0;mi<2;++mi){
        const int qrow = q0 + w*32 + mi*16 + quad*4;
        float inv[4];
        #pragma unroll
        for (int r=0;r<4;++r){
            float lt = l_[mi][r];
            lt += __shfl_xor(lt,1,16);
            lt += __shfl_xor(lt,2,16);
            lt += __shfl_xor(lt,4,16);
            lt += __shfl_xor(lt,8,16);
            inv[r] = 1.f/lt;
        }
        #pragma unroll
        for (int n8=0;n8<8;++n8)
            #pragma unroll
            for (int r=0;r<4;++r)
                yws[((size_t)(b*TT + qrow + r))*2048 + h*DD + n8*16 + l15] = f2b(o_[mi][n8][r]*inv[r]);
    }
}

// ---------------- Kernel 3: output projection (256x256 8-phase) ----------------
__global__ __launch_bounds__(512,2) void oproj_kernel(
    const u16t* __restrict__ y, const u16t* __restrict__ wob, float* __restrict__ out)
{
    __shared__ u16t lds[65536];
    const int tid = threadIdx.x;
    const int m0 = blockIdx.x*256, n0 = blockIdx.y*256;

    f32x4 acc[4][8];
    gemm256(y + (size_t)m0*CC, wob + (size_t)n0*CC, lds, acc, tid);

    const int w = tid>>6, quad = (tid>>4)&3, l15 = tid&15;
    const int wr = (w>>1)*64, wc = (w&1)*128;
    #pragma unroll
    for (int mi=0;mi<4;++mi){
        const int m = m0 + wr + mi*16 + quad*4;
        #pragma unroll
        for (int ni=0;ni<8;++ni){
            const int n = n0 + wc + ni*16 + l15;
            #pragma unroll
            for (int r=0;r<4;++r)
                out[(size_t)(m+r)*CC + n] = acc[mi][ni][r];
        }
    }
}

extern "C" void kernel_launch(void* const* d_in, const int* in_sizes, int n_in,
                              void* d_out, int out_size, void* d_ws, size_t ws_size,
                              hipStream_t stream) {
    const float* x    = (const float*)d_in[0];
    const float* cosp = (const float*)d_in[1];
    const float* sinp = (const float*)d_in[2];
    const float* Wq   = (const float*)d_in[3];
    const float* Wk   = (const float*)d_in[4];
    const float* Wv   = (const float*)d_in[5];
    const float* Wo   = (const float*)d_in[6];

    u16t* ws  = (u16t*)d_ws;
    u16t* xb  = ws;                          // 8388608 elems (aliased by yws after qkv)
    u16t* wqb = xb  + 8388608;               // 4194304
    u16t* wkb = wqb + 4194304;               // 1048576
    u16t* wvb = wkb + 1048576;               // 1048576
    u16t* wob = wvb + 1048576;               // 4194304
    u16t* qws = wob + 4194304;               // 8388608
    u16t* kws = qws + 8388608;               // 2097152
    u16t* vtw = kws + 2097152;               // 2097152
    u16t* yws = xb;                          // alias: xb dead after qkv_kernel
    float* out = (float*)d_out;

    cvt_kernel<<<dim3(9216), 256, 0, stream>>>(x, Wq, Wk, Wv, Wo, xb, wqb, wkb, wvb, wob);
    qkv_kernel<<<dim3(16, 12), 512, 0, stream>>>(xb, wqb, wkb, wvb, cosp, sinp, qws, kws, vtw);
    attn_kernel<<<dim3(16, 16, 2), 256, 0, stream>>>(qws, kws, vtw, yws);
    oproj_kernel<<<dim3(16, 8), 512, 0, stream>>>(yws, wob, out);
}

// Round 3
// 341.253 us; speedup vs baseline: 1.1656x; 1.1049x over previous
//
#include <hip/hip_runtime.h>
#include <hip/hip_bf16.h>

typedef unsigned short u16t;
typedef unsigned int   u32t;
typedef float  f32x4 __attribute__((ext_vector_type(4)));
typedef short  s16x8 __attribute__((ext_vector_type(8)));
typedef unsigned int u32x4 __attribute__((ext_vector_type(4)));
typedef float  f4 __attribute__((ext_vector_type(4)));

#define BB 2
#define TT 2048
#define CC 2048
#define HH 16
#define KVHN 4
#define DD 128
#define EPSV 1.1920929e-07f
#define SCALE 0.08838834764831845f
#define MFIX 12.0f   // fixed softmax max: |q.k|*SCALE <= sqrt(128)*(1+bf16 err) < 11.5

__device__ __forceinline__ float b2f(u16t u){ union{u32t i; float f;} x; x.i=((u32t)u)<<16; return x.f; }
__device__ __forceinline__ u16t f2b(float f){ union{float f; u32t i;} x; x.f=f; u32t r = x.i + 0x7fffu + ((x.i>>16)&1u); return (u16t)(r>>16); }
__device__ __forceinline__ u32t pk2(float a, float b){
    __hip_bfloat162 h = __float22bfloat162_rn(make_float2(a,b));
    u32t r; __builtin_memcpy(&r,&h,4); return r;
}
__device__ __forceinline__ s16x8 ldf(const u16t* p){ s16x8 r; __builtin_memcpy(&r,p,16); return r; }
__device__ __forceinline__ void st16(u16t* p, u32x4 v){ __builtin_memcpy(p,&v,16); }
__device__ __forceinline__ u32x4 ldg16(const u16t* p){ u32x4 r; __builtin_memcpy(&r,p,16); return r; }

// async global->LDS, 16B per lane; LDS dest = wave-uniform base + lane*16
typedef const __attribute__((address_space(1))) unsigned int ga_u32;
typedef __attribute__((address_space(3))) unsigned int ls_u32;
__device__ __forceinline__ void gl16(const u16t* g, u16t* l) {
    __builtin_amdgcn_global_load_lds((ga_u32*)(unsigned long long)(g),
                                     (ls_u32*)(unsigned int)(unsigned long long)(l),
                                     16, 0, 0);
}

#define BARRIER() __builtin_amdgcn_s_barrier()
#define SCHEDB()  __builtin_amdgcn_sched_barrier(0)
#define WAITLG0() asm volatile("s_waitcnt lgkmcnt(0)" ::: "memory")
#define WAITVM8() asm volatile("s_waitcnt vmcnt(8)" ::: "memory")
#define WAITVM4() asm volatile("s_waitcnt vmcnt(4)" ::: "memory")
#define WAITVM0() asm volatile("s_waitcnt vmcnt(0)" ::: "memory")

// ---------------- Kernel 0: fp32 -> bf16 conversion ----------------
__global__ __launch_bounds__(256) void cvt_kernel(
    const float* __restrict__ x,  const float* __restrict__ wq,
    const float* __restrict__ wk, const float* __restrict__ wv,
    const float* __restrict__ wo,
    u16t* __restrict__ xb, u16t* __restrict__ wqb, u16t* __restrict__ wkb,
    u16t* __restrict__ wvb, u16t* __restrict__ wob)
{
    size_t g = (size_t)blockIdx.x * 256 + threadIdx.x;
    const float* src; u16t* dst; size_t off;
    if      (g < 1048576) { src = x;  dst = xb;  off = g; }
    else if (g < 1572864) { src = wq; dst = wqb; off = g - 1048576; }
    else if (g < 1703936) { src = wk; dst = wkb; off = g - 1572864; }
    else if (g < 1835008) { src = wv; dst = wvb; off = g - 1703936; }
    else                  { src = wo; dst = wob; off = g - 1835008; }
    f4 a = *(const f4*)(src + off*8);
    f4 b = *(const f4*)(src + off*8 + 4);
    u32x4 o = { pk2(a[0],a[1]), pk2(a[2],a[3]), pk2(b[0],b[1]), pk2(b[2],b[3]) };
    st16(dst + off*8, o);
}

// ---------------- Shared 256x256 8-phase GEMM core (unchanged) ----------------
__device__ __forceinline__ void gemm256(
    const u16t* __restrict__ aPanel, const u16t* __restrict__ bPanel,
    u16t* lds, f32x4 (&acc)[4][8], const int tid)
{
    u16t* Abuf[2] = { lds,         lds + 32768 };
    u16t* Bbuf[2] = { lds + 16384, lds + 49152 };
    const int w = tid>>6, quad = (tid>>4)&3, l15 = tid&15;
    const int wr = (w>>1)*64, wc = (w&1)*128;
    const int gcol = (((tid&7) ^ ((tid>>3)&7)) << 3);
    const u16t* aB = aPanel + (size_t)(tid>>3)*CC + gcol;
    const u16t* bB = bPanel + (size_t)(tid>>3)*CC + gcol;

    #pragma unroll
    for (int i=0;i<4;++i)
        #pragma unroll
        for (int j=0;j<8;++j)
            #pragma unroll
            for (int r=0;r<4;++r) acc[i][j][r] = 0.f;

    #pragma unroll
    for (int i=0;i<4;++i){
        gl16(aB + (size_t)i*64*CC,      Abuf[0] + (i*512+tid)*8);
        gl16(bB + (size_t)i*64*CC,      Bbuf[0] + (i*512+tid)*8);
    }
    #pragma unroll
    for (int i=0;i<4;++i){
        gl16(aB + (size_t)i*64*CC + 64, Abuf[1] + (i*512+tid)*8);
        gl16(bB + (size_t)i*64*CC + 64, Bbuf[1] + (i*512+tid)*8);
    }

    s16x8 af[4], bf[4];
    #pragma unroll 2
    for (int kt=0; kt<32; ++kt){
        u16t* Ab = Abuf[kt&1];
        u16t* Bb = Bbuf[kt&1];
        if (kt == 31) { WAITVM0(); } else { WAITVM8(); }
        SCHEDB();
        BARRIER();
        #pragma unroll
        for (int ph=0; ph<4; ++ph){
            const int kh = ph>>1, nh = ph&1;
            if (nh == 0){
                #pragma unroll
                for (int mi=0;mi<4;++mi){
                    const int row = wr + mi*16 + l15;
                    af[mi] = ldf(Ab + row*64 + ((((kh<<2)|quad) ^ (row&7))<<3));
                }
            }
            #pragma unroll
            for (int ni=0;ni<4;++ni){
                const int row = wc + nh*64 + ni*16 + l15;
                bf[ni] = ldf(Bb + row*64 + ((((kh<<2)|quad) ^ (row&7))<<3));
            }
            BARRIER();
            WAITLG0();
            SCHEDB();
            __builtin_amdgcn_s_setprio(1);
            #pragma unroll
            for (int mi=0;mi<4;++mi)
                #pragma unroll
                for (int ni=0;ni<4;++ni)
                    acc[mi][(nh<<2)|ni] = __builtin_amdgcn_mfma_f32_16x16x32_bf16(
                        af[mi], bf[ni], acc[mi][(nh<<2)|ni], 0,0,0);
            __builtin_amdgcn_s_setprio(0);
            SCHEDB();
            BARRIER();
        }
        if (kt < 30){
            const int k0 = (kt+2)*64;
            #pragma unroll
            for (int i=0;i<4;++i){
                gl16(aB + (size_t)i*64*CC + k0, Ab + (i*512+tid)*8);
                gl16(bB + (size_t)i*64*CC + k0, Bb + (i*512+tid)*8);
            }
        }
    }
}

// ---------------- Kernel 1: QKV GEMM + in-register RoPE + RMSNorm (unchanged) ----------------
__global__ __launch_bounds__(512,2) void qkv_kernel(
    const u16t* __restrict__ xb, const u16t* __restrict__ wqb,
    const u16t* __restrict__ wkb, const u16t* __restrict__ wvb,
    const float* __restrict__ cosp, const float* __restrict__ sinp,
    u16t* __restrict__ qws, u16t* __restrict__ kws, u16t* __restrict__ vtw)
{
    __shared__ u16t lds[65536];
    const int tid = threadIdx.x;
    const int bx = blockIdx.x, by = blockIdx.y;
    const int m0 = bx*256;

    int type, headbase; const u16t* W;
    if (by < 8)       { type=0; W = wqb + (size_t)by*256*CC;      headbase = by*2; }
    else if (by < 10) { type=1; W = wkb + (size_t)(by-8)*256*CC;  headbase = (by-8)*2; }
    else              { type=2; W = wvb + (size_t)(by-10)*256*CC; headbase = (by-10)*2; }

    f32x4 acc[4][8];
    gemm256(xb + (size_t)m0*CC, W, lds, acc, tid);

    const int w = tid>>6, quad = (tid>>4)&3, l15 = tid&15;
    const int wr = (w>>1)*64, wn = w&1;
    const int head = headbase + wn;
    const int bb = bx>>3;
    const int ttb = (m0 + wr) & 2047;

    if (type == 2){
        u16t* vb = vtw + (size_t)(bb*KVHN+head)*DD*TT;
        #pragma unroll
        for (int mi=0;mi<4;++mi){
            const int tt = ttb + mi*16 + quad*4;
            #pragma unroll
            for (int ni=0;ni<8;++ni){
                const int d = ni*16 + l15;
                u16t o[4];
                #pragma unroll
                for (int r=0;r<4;++r) o[r] = f2b(acc[mi][ni][r]);
                __builtin_memcpy(vb + (size_t)d*TT + tt, o, 8);
            }
        }
    } else {
        u16t* dst = (type==0) ? (qws + (size_t)(bb*HH+head)*TT*DD)
                              : (kws + (size_t)(bb*KVHN+head)*TT*DD);
        #pragma unroll
        for (int mi=0;mi<4;++mi){
            const int tt0 = ttb + mi*16 + quad*4;
            float ss[4] = {0.f,0.f,0.f,0.f};
            #pragma unroll
            for (int ni=0;ni<8;++ni)
                #pragma unroll
                for (int r=0;r<4;++r) ss[r] += acc[mi][ni][r]*acc[mi][ni][r];
            float rms[4];
            #pragma unroll
            for (int r=0;r<4;++r){
                float s = ss[r];
                s += __shfl_xor(s, 1, 16);
                s += __shfl_xor(s, 2, 16);
                s += __shfl_xor(s, 4, 16);
                s += __shfl_xor(s, 8, 16);
                rms[r] = rsqrtf(s*(1.f/128.f) + EPSV);
            }
            #pragma unroll
            for (int ni=0;ni<4;++ni){
                const int j = ni*16 + l15;
                #pragma unroll
                for (int r=0;r<4;++r){
                    const int tt = tt0 + r;
                    const float c = cosp[tt*64 + j];
                    const float s = sinp[tt*64 + j];
                    const float z1 = acc[mi][ni][r], z2 = acc[mi][ni+4][r];
                    dst[(size_t)tt*DD + j]      = f2b((z1*c + z2*s)*rms[r]);
                    dst[(size_t)tt*DD + j + 64] = f2b((z2*c - z1*s)*rms[r]);
                }
            }
        }
    }
}

// ---------------- Kernel 2: causal flash attention ----------------
// 512 threads = 8 waves. Waves 0-3 own q-tile (15-bx) [long], waves 4-7 own
// q-tile bx [short] -> every block does exactly 17 q-tile-kt of compute and
// K/V staging is shared. Grid (8,16,2) = 256 blocks = 1/CU, balanced.
// K/V double-buffered via global_load_lds with counted vmcnt (T3+T4);
// XOR-granule swizzle (rule 21): inverse-swizzled global src + swizzled read.
// Q fragments load straight from global to registers (no LDS stage).
// FIX vs r2: prologue K tile-1 staging used a COLUMN (+64 on d) offset instead
// of a ROW offset ((krow+64)*DD) — K is [t][d]; only V (transposed, [d][t])
// takes +64 on the fast axis. kt=1 read garbage K. Now (krow+64/96)*DD.
__global__ __launch_bounds__(512,2) void attn_kernel(
    const u16t* __restrict__ qws, const u16t* __restrict__ kws,
    const u16t* __restrict__ vtw, u16t* __restrict__ yws)
{
    __shared__ u16t lds[49152];   // 96 KiB
    // u16 offsets: K0 0, K1 8192, V0 16384, V1 24576, Ps 32768 ([256][64] swz)
    u16t* Ps = lds + 32768;

    const int tid = threadIdx.x;
    const int w = tid>>6, lane = tid&63, quad = lane>>4, l15 = lane&15;
    const int bx = blockIdx.x, h = blockIdx.y, b = blockIdx.z, kvh = h>>2;

    const int qti    = (w < 4) ? (15 - bx) : bx;
    const int qwbase = qti*128 + (w&3)*32;        // absolute first q-row of this wave
    const int nkt    = (16 - bx)*2;               // staged K/V tiles (covers both q-tiles)

    const u16t* kb = kws + (size_t)(b*KVHN+kvh)*TT*DD;
    const u16t* vb = vtw + (size_t)(b*KVHN+kvh)*DD*TT;

    // per-thread staging constants (inverse-swizzled global column granule)
    const int krow = tid>>4;                        // 0..31 (+32 second iter)
    const int kcg  = (tid&15) ^ ((tid>>4)&7);
    const int vrow = tid>>3;                        // 0..63 (+64 second iter)
    const int vcg  = (tid&7)  ^ ((tid>>3)&7);

    // Q fragments: direct global->reg
    const u16t* qp = qws + ((size_t)(b*HH+h)*TT + qwbase + l15)*DD + quad*8;
    s16x8 qf[2][4];
    #pragma unroll
    for (int mi=0;mi<2;++mi)
        #pragma unroll
        for (int kq=0;kq<4;++kq)
            qf[mi][kq] = ldf(qp + (size_t)mi*16*DD + kq*32);

    // prologue: stage tiles 0 and 1 (4 gl16/thread each)
    {
        u16t* Kd = lds;        u16t* Vd = lds + 16384;
        gl16(kb + (size_t)(krow)*DD + kcg*8,        Kd + tid*8);
        gl16(kb + (size_t)(krow+32)*DD + kcg*8,     Kd + (512+tid)*8);
        gl16(vb + (size_t)(vrow)*TT + vcg*8,        Vd + tid*8);
        gl16(vb + (size_t)(vrow+64)*TT + vcg*8,     Vd + (512+tid)*8);
        SCHEDB();   // keep tile-0 staging strictly before tile-1 (vmcnt ledger)
        Kd = lds + 8192;       Vd = lds + 24576;
        gl16(kb + (size_t)(krow+64)*DD + kcg*8,      Kd + tid*8);
        gl16(kb + (size_t)(krow+96)*DD + kcg*8,      Kd + (512+tid)*8);
        gl16(vb + (size_t)(vrow)*TT + 64 + vcg*8,    Vd + tid*8);
        gl16(vb + (size_t)(vrow+64)*TT + 64 + vcg*8, Vd + (512+tid)*8);
    }

    f32x4 o_[2][8];
    float l_[2][4];
    #pragma unroll
    for (int mi=0;mi<2;++mi){
        #pragma unroll
        for (int r=0;r<4;++r) l_[mi][r] = 0.f;
        #pragma unroll
        for (int n8=0;n8<8;++n8)
            #pragma unroll
            for (int r=0;r<4;++r) o_[mi][n8][r] = 0.f;
    }

    const int swz = (l15&7)<<3;   // read-side XOR (u16 units) for K/V/Ps b128 reads

    for (int kt=0; kt<nkt; ++kt){
        const int k0 = kt*64;
        if (kt+1 == nkt) { WAITVM0(); } else { WAITVM4(); }
        SCHEDB();
        BARRIER();                                   // tile kt visible to all waves
        if (k0 <= qwbase + 31) {
            const u16t* Ks = (kt&1) ? (lds + 8192)  : lds;           // [64][128] swz
            const u16t* Vt = (kt&1) ? (lds + 24576) : (lds + 16384); // [128][64] swz

            // S = Q K^T
            f32x4 s[2][4];
            #pragma unroll
            for (int mi=0;mi<2;++mi)
                #pragma unroll
                for (int ni=0;ni<4;++ni)
                    #pragma unroll
                    for (int r=0;r<4;++r) s[mi][ni][r] = 0.f;
            #pragma unroll
            for (int kq=0;kq<4;++kq){
                s16x8 kf[4];
                #pragma unroll
                for (int ni=0;ni<4;++ni)
                    kf[ni] = ldf(Ks + (ni*16+l15)*128 + (((kq*4+quad)<<3) ^ swz));
                __builtin_amdgcn_s_setprio(1);
                #pragma unroll
                for (int mi=0;mi<2;++mi)
                    #pragma unroll
                    for (int ni=0;ni<4;++ni)
                        s[mi][ni] = __builtin_amdgcn_mfma_f32_16x16x32_bf16(qf[mi][kq], kf[ni], s[mi][ni], 0,0,0);
                __builtin_amdgcn_s_setprio(0);
            }

            // fixed-max softmax: p = exp(s*SCALE - 12)
            const bool need_mask = (k0 + 63) > qwbase;
            #pragma unroll
            for (int mi=0;mi<2;++mi){
                const int qrow = qwbase + mi*16 + quad*4;
                #pragma unroll
                for (int ni=0;ni<4;++ni){
                    const int kcol = k0 + ni*16 + l15;
                    #pragma unroll
                    for (int r=0;r<4;++r){
                        float p = __expf(__builtin_fmaf(s[mi][ni][r], SCALE, -MFIX));
                        if (need_mask && kcol > qrow + r) p = 0.f;
                        l_[mi][r] += p;
                        const int rw = w*32 + mi*16 + quad*4 + r;
                        Ps[rw*64 + ((ni*16+l15) ^ (((quad*4+r)&7)<<3))] = f2b(p);
                    }
                }
            }

            // O += P V  (same-wave LDS round-trip; DS ops in-order, no barrier)
            #pragma unroll
            for (int ks=0;ks<2;++ks){
                s16x8 pf[2];
                #pragma unroll
                for (int mi=0;mi<2;++mi)
                    pf[mi] = ldf(Ps + (w*32+mi*16+l15)*64 + (((ks*4+quad)<<3) ^ swz));
                __builtin_amdgcn_s_setprio(1);
                #pragma unroll
                for (int n8=0;n8<8;++n8){
                    s16x8 vf = ldf(Vt + (n8*16+l15)*64 + (((ks*4+quad)<<3) ^ swz));
                    #pragma unroll
                    for (int mi=0;mi<2;++mi)
                        o_[mi][n8] = __builtin_amdgcn_mfma_f32_16x16x32_bf16(pf[mi], vf, o_[mi][n8], 0,0,0);
                }
                __builtin_amdgcn_s_setprio(0);
            }
        }
        BARRIER();                                   // all reads of buf (kt&1) done
        if (kt+2 < nkt){                             // restage just-freed buffer
            const int kn = (kt+2)*64;
            u16t* Kd = (kt&1) ? (lds + 8192)  : lds;
            u16t* Vd = (kt&1) ? (lds + 24576) : (lds + 16384);
            gl16(kb + (size_t)(kn+krow)*DD + kcg*8,      Kd + tid*8);
            gl16(kb + (size_t)(kn+krow+32)*DD + kcg*8,   Kd + (512+tid)*8);
            gl16(vb + (size_t)(vrow)*TT + kn + vcg*8,    Vd + tid*8);
            gl16(vb + (size_t)(vrow+64)*TT + kn + vcg*8, Vd + (512+tid)*8);
        }
    }

    // epilogue: reduce l across the 16 col-lanes, normalize, store y[b][t][h*128+d]
    #pragma unroll
    for (int mi=0;mi<2;++mi){
        const int qrow = qwbase + mi*16 + quad*4;
        float inv[4];
        #pragma unroll
        for (int r=0;r<4;++r){
            float lt = l_[mi][r];
            lt += __shfl_xor(lt,1,16);
            lt += __shfl_xor(lt,2,16);
            lt += __shfl_xor(lt,4,16);
            lt += __shfl_xor(lt,8,16);
            inv[r] = 1.f/lt;
        }
        #pragma unroll
        for (int n8=0;n8<8;++n8)
            #pragma unroll
            for (int r=0;r<4;++r)
                yws[((size_t)(b*TT + qrow + r))*2048 + h*DD + n8*16 + l15] = f2b(o_[mi][n8][r]*inv[r]);
    }
}

// ---------------- Kernel 3: output projection (256x256 8-phase, unchanged) ----------------
__global__ __launch_bounds__(512,2) void oproj_kernel(
    const u16t* __restrict__ y, const u16t* __restrict__ wob, float* __restrict__ out)
{
    __shared__ u16t lds[65536];
    const int tid = threadIdx.x;
    const int m0 = blockIdx.x*256, n0 = blockIdx.y*256;

    f32x4 acc[4][8];
    gemm256(y + (size_t)m0*CC, wob + (size_t)n0*CC, lds, acc, tid);

    const int w = tid>>6, quad = (tid>>4)&3, l15 = tid&15;
    const int wr = (w>>1)*64, wc = (w&1)*128;
    #pragma unroll
    for (int mi=0;mi<4;++mi){
        const int m = m0 + wr + mi*16 + quad*4;
        #pragma unroll
        for (int ni=0;ni<8;++ni){
            const int n = n0 + wc + ni*16 + l15;
            #pragma unroll
            for (int r=0;r<4;++r)
                out[(size_t)(m+r)*CC + n] = acc[mi][ni][r];
        }
    }
}

extern "C" void kernel_launch(void* const* d_in, const int* in_sizes, int n_in,
                              void* d_out, int out_size, void* d_ws, size_t ws_size,
                              hipStream_t stream) {
    const float* x    = (const float*)d_in[0];
    const float* cosp = (const float*)d_in[1];
    const float* sinp = (const float*)d_in[2];
    const float* Wq   = (const float*)d_in[3];
    const float* Wk   = (const float*)d_in[4];
    const float* Wv   = (const float*)d_in[5];
    const float* Wo   = (const float*)d_in[6];

    u16t* ws  = (u16t*)d_ws;
    u16t* xb  = ws;                          // 8388608 elems (aliased by yws after qkv)
    u16t* wqb = xb  + 8388608;               // 4194304
    u16t* wkb = wqb + 4194304;               // 1048576
    u16t* wvb = wkb + 1048576;               // 1048576
    u16t* wob = wvb + 1048576;               // 4194304
    u16t* qws = wob + 4194304;               // 8388608
    u16t* kws = qws + 8388608;               // 2097152
    u16t* vtw = kws + 2097152;               // 2097152
    u16t* yws = xb;                          // alias: xb dead after qkv_kernel
    float* out = (float*)d_out;

    cvt_kernel<<<dim3(9216), 256, 0, stream>>>(x, Wq, Wk, Wv, Wo, xb, wqb, wkb, wvb, wob);
    qkv_kernel<<<dim3(16, 12), 512, 0, stream>>>(xb, wqb, wkb, wvb, cosp, sinp, qws, kws, vtw);
    attn_kernel<<<dim3(8, 16, 2), 512, 0, stream>>>(qws, kws, vtw, yws);
    oproj_kernel<<<dim3(16, 8), 512, 0, stream>>>(yws, wob, out);
}